// Round 10
// baseline (207.834 us; speedup 1.0000x reference)
//
#include <hip/hip_runtime.h>
#include <math.h>

#define NHEADS 8
#define DHEAD  64
#define HIDDEN 512     // NHEADS*DHEAD
#define CIN    256
#define NTOK   1024    // 32*32
#define QK_SCALE 10.0f
#define LOG2E 1.44269504088896f
// softmax shift: sim = 10*cos(q,k) <= ~10.1 (bf16 slack); constant shift is exact
#define MSHIFT 10.5f
#define MBIAS  (-MSHIFT * LOG2E)
#define NSPLIT 4       // key splits (256 keys each)

typedef __bf16 bf16x8 __attribute__((ext_vector_type(8)));
typedef float  f32x4  __attribute__((ext_vector_type(4)));
typedef unsigned u32x4 __attribute__((ext_vector_type(4)));
typedef unsigned short u16x8 __attribute__((ext_vector_type(8)));
typedef unsigned short u16x4 __attribute__((ext_vector_type(4)));

__device__ inline unsigned short f2bf(float f) {
    unsigned u = __builtin_bit_cast(unsigned, f);
    u = (u + 0x7FFFu + ((u >> 16) & 1u)) >> 16;   // RNE
    return (unsigned short)u;
}

// pack two floats -> one u32 of 2 bf16 (RNE; epilogue only)
__device__ inline unsigned pk2(float a, float b) {
    return (unsigned)f2bf(a) | ((unsigned)f2bf(b) << 16);
}

// TRUNCATION pack (3 ops) — used in the attn hot loop; lsum uses the same
// truncated values so the bias cancels in O/l.
__device__ inline unsigned pk2t(float a, float b) {
    return (__builtin_bit_cast(unsigned, a) >> 16) |
           (__builtin_bit_cast(unsigned, b) & 0xFFFF0000u);
}
__device__ inline float trunc_bf(float f) {
    return __builtin_bit_cast(float, __builtin_bit_cast(unsigned, f) & 0xFFFF0000u);
}

__device__ inline float bf2f(unsigned short u) {
    return __builtin_bit_cast(float, (unsigned)u << 16);
}

__device__ inline bf16x8 cvt8(const float* p) {
    float4 a = *(const float4*)p;
    float4 b = *(const float4*)(p + 4);
    u16x8 t;
    t[0] = f2bf(a.x); t[1] = f2bf(a.y); t[2] = f2bf(a.z); t[3] = f2bf(a.w);
    t[4] = f2bf(b.x); t[5] = f2bf(b.y); t[6] = f2bf(b.z); t[7] = f2bf(b.w);
    return __builtin_bit_cast(bf16x8, t);
}

// ---------------------------------------------------------------------------
// x (8,256,1024) fp32 d-major -> xt (8,1024,256) bf16 token-major.
// ---------------------------------------------------------------------------
__global__ __launch_bounds__(256)
void cvt_x_kernel(const float* __restrict__ x, unsigned short* __restrict__ xt) {
    const int b  = blockIdx.z;
    const int c0 = blockIdx.y * 64;
    const int n0 = blockIdx.x * 64;
    const float* src = x + ((size_t)b * CIN + c0) * NTOK + n0;
    unsigned short* dst = xt + ((size_t)b * NTOK + n0) * CIN + c0;

    __shared__ float T[64][65];
    const int t = threadIdx.x;
    {
        const int nq = t & 15, cg = t >> 4;
        #pragma unroll
        for (int rr = 0; rr < 4; ++rr) {
            const int c = cg + rr * 16;
            float4 v = *(const float4*)(src + (size_t)c * NTOK + nq * 4);
            T[c][nq * 4 + 0] = v.x;
            T[c][nq * 4 + 1] = v.y;
            T[c][nq * 4 + 2] = v.z;
            T[c][nq * 4 + 3] = v.w;
        }
    }
    __syncthreads();
    {
        const int n = t >> 2, cq = t & 3;
        alignas(16) unsigned short tmp[16];
        #pragma unroll
        for (int e = 0; e < 16; ++e)
            tmp[e] = f2bf(T[cq * 16 + e][n]);
        *(uint4*)(dst + (size_t)n * CIN + cq * 16)     = *(uint4*)&tmp[0];
        *(uint4*)(dst + (size_t)n * CIN + cq * 16 + 8) = *(uint4*)&tmp[8];
    }
}

// ---------------------------------------------------------------------------
// Weights fp32 -> bf16 (row-major preserved).
// ---------------------------------------------------------------------------
__global__ __launch_bounds__(256)
void cvt_w_kernel(const float* __restrict__ wq, const float* __restrict__ wo,
                  unsigned short* __restrict__ wqb, unsigned short* __restrict__ wob) {
    const size_t i = ((size_t)blockIdx.x * 256 + threadIdx.x) * 8;
    if (i < (size_t)1536 * 256) {
        *(bf16x8*)(wqb + i) = cvt8(wq + i);
    } else {
        const size_t j = i - (size_t)1536 * 256;
        *(bf16x8*)(wob + j) = cvt8(wo + j);
    }
}

// ---------------------------------------------------------------------------
// GEMM1: qkv = w_qkv (1536x256) x x (256x1024) per batch, bf16 MFMA.
// Epilogues: q/k -> token-major fp32 qt + sumsq atomics;
//            v -> bf16 d-major vb, KEY-PERMUTED within 32-token blocks
//            (sigma matches PV's MFMA k-slot layout).
// ---------------------------------------------------------------------------
__global__ __launch_bounds__(256)
void gemm1_kernel(const unsigned short* __restrict__ wqb,
                  const unsigned short* __restrict__ xt,
                  float* __restrict__ qt,
                  unsigned short* __restrict__ vb,
                  float* __restrict__ ss) {
    const int b  = blockIdx.z;
    const int bm = blockIdx.y * 128;
    const int bn = blockIdx.x * 128;
    const int wave = threadIdx.x >> 6, lane = threadIdx.x & 63;
    const int lo = lane & 15, hi = lane >> 4;
    const int wm = bm + (wave >> 1) * 64;
    const int wn = bn + (wave & 1) * 64;

    const unsigned short* Ab = wqb + (size_t)(wm + lo) * CIN + hi * 8;
    const unsigned short* Bb = xt + ((size_t)b * NTOK + wn + lo) * CIN + hi * 8;

    f32x4 acc[4][4];
    #pragma unroll
    for (int mi = 0; mi < 4; ++mi)
        #pragma unroll
        for (int ni = 0; ni < 4; ++ni) acc[mi][ni] = (f32x4){0.f, 0.f, 0.f, 0.f};

    for (int k0 = 0; k0 < CIN; k0 += 32) {
        bf16x8 a[4], bf[4];
        #pragma unroll
        for (int mi = 0; mi < 4; ++mi) a[mi]  = *(const bf16x8*)(Ab + (size_t)mi * 16 * CIN + k0);
        #pragma unroll
        for (int ni = 0; ni < 4; ++ni) bf[ni] = *(const bf16x8*)(Bb + (size_t)ni * 16 * CIN + k0);
        #pragma unroll
        for (int mi = 0; mi < 4; ++mi)
            #pragma unroll
            for (int ni = 0; ni < 4; ++ni)
                acc[mi][ni] = __builtin_amdgcn_mfma_f32_16x16x32_bf16(a[mi], bf[ni], acc[mi][ni], 0, 0, 0);
    }

    __shared__ unsigned short VL[4][32][72];

    if (bm < 1024) {
        const int isK = (wm >= 512) ? 1 : 0;
        const int ch0 = wm & 511;
        const int head = ch0 >> 6;
        float* dst = qt + (((size_t)isK * 64 + b * 8 + head) * NTOK) * DHEAD;
        #pragma unroll
        for (int mi = 0; mi < 4; ++mi) {
            const int d = mi * 16 + hi * 4;
            #pragma unroll
            for (int ni = 0; ni < 4; ++ni) {
                const int n = wn + ni * 16 + lo;
                *(f32x4*)(dst + (size_t)n * DHEAD + d) = acc[mi][ni];
            }
        }
        float p[4][4];
        #pragma unroll
        for (int mi = 0; mi < 4; ++mi)
            #pragma unroll
            for (int r = 0; r < 4; ++r) {
                float s = 0.f;
                #pragma unroll
                for (int ni = 0; ni < 4; ++ni) s += acc[mi][ni][r] * acc[mi][ni][r];
                p[mi][r] = s;
            }
        #pragma unroll
        for (int off = 1; off < 16; off <<= 1)
            #pragma unroll
            for (int mi = 0; mi < 4; ++mi)
                #pragma unroll
                for (int r = 0; r < 4; ++r)
                    p[mi][r] += __shfl_xor(p[mi][r], off, 64);
        if (lo == 0) {
            #pragma unroll
            for (int mi = 0; mi < 4; ++mi)
                #pragma unroll
                for (int r = 0; r < 4; ++r)
                    atomicAdd(&ss[(size_t)b * 1024 + isK * 512 + ch0 + mi * 16 + hi * 4 + r], p[mi][r]);
        }
    } else {
        const int ch0 = wm - 1024;
        #pragma unroll
        for (int half = 0; half < 2; ++half) {
            #pragma unroll
            for (int mm = 0; mm < 2; ++mm) {
                const int mi = half * 2 + mm;
                #pragma unroll
                for (int ni = 0; ni < 4; ++ni)
                    #pragma unroll
                    for (int r = 0; r < 4; ++r)
                        VL[wave][mm * 16 + hi * 4 + r][ni * 16 + lo] = f2bf(acc[mi][ni][r]);
            }
            // wave-synchronous readback WITH key-permutation sigma
            #pragma unroll
            for (int i = 0; i < 4; ++i) {
                const int flat = i * 64 + lane;
                const int row = flat >> 3, c = flat & 7;
                const int tb = c >> 2, hg = c & 3;
                const uint2 vlo = *(uint2*)&VL[wave][row][tb * 32 + hg * 4];
                const uint2 vhi = *(uint2*)&VL[wave][row][tb * 32 + hg * 4 + 16];
                uint4 v = make_uint4(vlo.x, vlo.y, vhi.x, vhi.y);
                const int ch = ch0 + half * 32 + row;
                *(uint4*)(vb + ((size_t)b * HIDDEN + ch) * NTOK + wn + c * 8) = v;
            }
        }
    }
}

// ---------------------------------------------------------------------------
// qt fp32 [isK][bh][n][d] -> qs/ks bf16 [bh][n][d], scaled by rsqrt(ss) (x10 q).
// ---------------------------------------------------------------------------
__global__ __launch_bounds__(256)
void scale_cvt_kernel(const float* __restrict__ qt, const float* __restrict__ ss,
                      unsigned short* __restrict__ qs, unsigned short* __restrict__ ks) {
    const size_t idx = ((size_t)blockIdx.x * 256 + threadIdx.x) * 8;
    const size_t half = (size_t)64 * NTOK * DHEAD;
    const int isK = idx >= half;
    const size_t rem = idx - (size_t)isK * half;
    const int bh = (int)(rem >> 16);
    const int d0 = (int)(rem & 63);
    const int b  = bh >> 3;
    const int ch = isK * 512 + (bh & 7) * 64 + d0;
    const float scl = isK ? 1.0f : QK_SCALE;

    const float* ip = qt + idx;
    float4 v0 = *(const float4*)ip;
    float4 v1 = *(const float4*)(ip + 4);
    float4 q0 = *(const float4*)(ss + (size_t)b * 1024 + ch);
    float4 q1 = *(const float4*)(ss + (size_t)b * 1024 + ch + 4);
    float4 s0, s1;
    s0.x = 1.0f / fmaxf(sqrtf(q0.x), 1e-12f); s0.y = 1.0f / fmaxf(sqrtf(q0.y), 1e-12f);
    s0.z = 1.0f / fmaxf(sqrtf(q0.z), 1e-12f); s0.w = 1.0f / fmaxf(sqrtf(q0.w), 1e-12f);
    s1.x = 1.0f / fmaxf(sqrtf(q1.x), 1e-12f); s1.y = 1.0f / fmaxf(sqrtf(q1.y), 1e-12f);
    s1.z = 1.0f / fmaxf(sqrtf(q1.z), 1e-12f); s1.w = 1.0f / fmaxf(sqrtf(q1.w), 1e-12f);
    u16x8 t;
    t[0] = f2bf(v0.x * s0.x * scl); t[1] = f2bf(v0.y * s0.y * scl);
    t[2] = f2bf(v0.z * s0.z * scl); t[3] = f2bf(v0.w * s0.w * scl);
    t[4] = f2bf(v1.x * s1.x * scl); t[5] = f2bf(v1.y * s1.y * scl);
    t[6] = f2bf(v1.z * s1.z * scl); t[7] = f2bf(v1.w * s1.w * scl);
    *(u16x8*)((isK ? ks : qs) + rem) = t;
}

// ---------------------------------------------------------------------------
// MFMA flash attention, split-K over keys (4 x 256), fixed shift M=10.5.
// SWAPPED operands; P lane-local in registers; PV k-permutation pre-baked
// into vb. NO LDS, NO barriers, NO in-loop cross-lane ops.
// In-loop pack = truncation (3 ops/pair); lsum uses the SAME truncated
// values so the ratio O/l is unbiased.
// Partials: po bf16 [split][bh][row][d] (unnormalized), pml fp32 = l per row.
// ---------------------------------------------------------------------------
__global__ __launch_bounds__(128)
void attn_mfma_kernel(const unsigned short* __restrict__ qs,
                      const unsigned short* __restrict__ ks,
                      const unsigned short* __restrict__ vb,
                      unsigned short* __restrict__ po, float* __restrict__ pml) {
    const int hw = blockIdx.x;                    // 4096 blocks
    const int virt = (hw & 7) * 512 + (hw >> 3);  // XCD-chunked: 8 bh per XCD
    const int bh  = virt >> 6;
    const int sub = virt & 63;
    const int it  = sub & 15;
    const int js  = sub >> 4;                     // key-split index 0..3
    const int b = bh >> 3, h = bh & 7;

    const int lane = threadIdx.x & 63;
    const int wave = threadIdx.x >> 6;            // 0..1
    const int lo = lane & 15;
    const int hi = lane >> 4;
    const int iw = it * 64 + wave * 32;

    const unsigned short* qbh = qs + (size_t)bh * NTOK * DHEAD;
    const unsigned short* kbh = ks + (size_t)bh * NTOK * DHEAD;
    const unsigned short* vbh = vb + ((size_t)b * HIDDEN + h * DHEAD) * NTOK;

    // Q fragments (once): frag f covers q-rows iw+f*16+lo
    bf16x8 aQ[2][2];
    #pragma unroll
    for (int f = 0; f < 2; ++f) {
        const unsigned short* qp = qbh + (size_t)(iw + f * 16 + lo) * DHEAD + hi * 8;
        aQ[f][0] = *(const bf16x8*)qp;
        aQ[f][1] = *(const bf16x8*)(qp + 32);
    }

    float lsum4[2][4];
    #pragma unroll
    for (int f = 0; f < 2; ++f)
        #pragma unroll
        for (int r = 0; r < 4; ++r) lsum4[f][r] = 0.0f;
    f32x4 acc[2][4];
    #pragma unroll
    for (int f = 0; f < 2; ++f)
        #pragma unroll
        for (int ds = 0; ds < 4; ++ds) acc[f][ds] = (f32x4){0.f, 0.f, 0.f, 0.f};

    #pragma unroll 2
    for (int jt = 0; jt < 4; ++jt) {
        const int j0 = js * 256 + jt * 64;

        // --- V A-fragments: contiguous bf16x8 (perm pre-baked in vb layout)
        bf16x8 bV[4][2];
        #pragma unroll
        for (int ds = 0; ds < 4; ++ds) {
            const unsigned short* vp = vbh + (size_t)(ds * 16 + lo) * NTOK + j0 + hi * 8;
            bV[ds][0] = *(const bf16x8*)vp;
            bV[ds][1] = *(const bf16x8*)(vp + 32);
        }

        // --- K fragments
        bf16x8 bK[4][2];
        #pragma unroll
        for (int jj = 0; jj < 4; ++jj) {
            const unsigned short* kp = kbh + (size_t)(j0 + jj * 16 + lo) * DHEAD + hi * 8;
            bK[jj][0] = *(const bf16x8*)kp;
            bK[jj][1] = *(const bf16x8*)(kp + 32);
        }

        // --- QK^T swapped: s[f][jj][r] = P[q=lo][k = jj*16 + hi*4 + r]
        f32x4 s[2][4];
        __builtin_amdgcn_s_setprio(1);
        #pragma unroll
        for (int jj = 0; jj < 4; ++jj)
            #pragma unroll
            for (int f = 0; f < 2; ++f) {
                f32x4 c = (f32x4){0.f, 0.f, 0.f, 0.f};
                c = __builtin_amdgcn_mfma_f32_16x16x32_bf16(bK[jj][0], aQ[f][0], c, 0, 0, 0);
                c = __builtin_amdgcn_mfma_f32_16x16x32_bf16(bK[jj][1], aQ[f][1], c, 0, 0, 0);
                s[f][jj] = c;
            }
        __builtin_amdgcn_s_setprio(0);

        // --- p = exp(s - 10.5); truncated lsum; truncation pack (3 ops/pair)
        unsigned pw[2][2][4];   // [f][t][word]
        #pragma unroll
        for (int f = 0; f < 2; ++f) {
            #pragma unroll
            for (int jj = 0; jj < 4; ++jj)
                #pragma unroll
                for (int r = 0; r < 4; ++r) {
                    const float p = __builtin_amdgcn_exp2f(fmaf(s[f][jj][r], LOG2E, MBIAS));
                    s[f][jj][r] = p;
                    lsum4[f][r] += trunc_bf(p);
                }
            #pragma unroll
            for (int t = 0; t < 2; ++t) {
                pw[f][t][0] = pk2t(s[f][2 * t][0],     s[f][2 * t][1]);
                pw[f][t][1] = pk2t(s[f][2 * t][2],     s[f][2 * t][3]);
                pw[f][t][2] = pk2t(s[f][2 * t + 1][0], s[f][2 * t + 1][1]);
                pw[f][t][3] = pk2t(s[f][2 * t + 1][2], s[f][2 * t + 1][3]);
            }
        }

        // --- PV swapped: acc[f][ds] += V-frag x P-frag
        __builtin_amdgcn_s_setprio(1);
        #pragma unroll
        for (int ds = 0; ds < 4; ++ds)
            #pragma unroll
            for (int f = 0; f < 2; ++f)
                #pragma unroll
                for (int t = 0; t < 2; ++t) {
                    const bf16x8 bp = __builtin_bit_cast(bf16x8,
                        (u32x4){pw[f][t][0], pw[f][t][1], pw[f][t][2], pw[f][t][3]});
                    acc[f][ds] = __builtin_amdgcn_mfma_f32_16x16x32_bf16(bV[ds][t], bp, acc[f][ds], 0, 0, 0);
                }
        __builtin_amdgcn_s_setprio(0);
    }

    // --- fold 4 lsum chains, then 2 cross-lane rounds (once per kernel)
    float lsum[2];
    #pragma unroll
    for (int f = 0; f < 2; ++f) {
        lsum[f] = (lsum4[f][0] + lsum4[f][1]) + (lsum4[f][2] + lsum4[f][3]);
        lsum[f] += __shfl_xor(lsum[f], 16, 64);
        lsum[f] += __shfl_xor(lsum[f], 32, 64);
    }

    // --- epilogue: direct register stores, O[q = iw+f*16+lo][d = ds*16+hi*4+r]
    unsigned short* pob = po + ((size_t)(js * 64 + bh) * NTOK + iw) * DHEAD;
    #pragma unroll
    for (int f = 0; f < 2; ++f) {
        #pragma unroll
        for (int ds = 0; ds < 4; ++ds) {
            uint2 w;
            w.x = pk2(acc[f][ds][0], acc[f][ds][1]);
            w.y = pk2(acc[f][ds][2], acc[f][ds][3]);
            *(uint2*)(pob + (size_t)(f * 16 + lo) * DHEAD + ds * 16 + hi * 4) = w;
        }
        if (hi == 0)
            pml[(size_t)(js * 64 + bh) * NTOK + iw + f * 16 + lo] = lsum[f];
    }
}

// ---------------------------------------------------------------------------
// Combine the four key-split partials -> attn_t bf16 token-major [b][n][512].
// Shared fixed shift => out = (o0+o1+o2+o3) / (l0+l1+l2+l3).
// ---------------------------------------------------------------------------
__global__ __launch_bounds__(256)
void combine_kernel(const unsigned short* __restrict__ po, const float* __restrict__ pml,
                    unsigned short* __restrict__ attn_t) {
    const size_t fl = ((size_t)blockIdx.x * 256 + threadIdx.x) * 8;
    const int bh  = (int)(fl >> 16);
    const int rem = (int)(fl & 65535);
    const int row = rem >> 6;
    const int d   = rem & 63;
    const int b = bh >> 3, h = bh & 7;
    const size_t SS = (size_t)64 * NTOK * DHEAD;

    float l = 0.f;
    #pragma unroll
    for (int s = 0; s < NSPLIT; ++s)
        l += pml[(size_t)(s * 64 + bh) * NTOK + row];
    const float inv = 1.0f / l;

    float o[8] = {};
    #pragma unroll
    for (int s = 0; s < NSPLIT; ++s) {
        const u16x8 v = *(const u16x8*)(po + s * SS + fl);
        #pragma unroll
        for (int e = 0; e < 8; ++e) o[e] += bf2f(v[e]);
    }
    u16x8 r;
    #pragma unroll
    for (int e = 0; e < 8; ++e) r[e] = f2bf(o[e] * inv);
    *(u16x8*)(attn_t + ((size_t)b * NTOK + row) * HIDDEN + h * DHEAD + d) = r;
}

// ---------------------------------------------------------------------------
// GEMM2: out = w_out (256x512) x attn_t^T + bias, bf16 MFMA.
// ---------------------------------------------------------------------------
__global__ __launch_bounds__(128)
void gemm2_kernel(const unsigned short* __restrict__ wob,
                  const unsigned short* __restrict__ attn_t,
                  const float* __restrict__ b_out,
                  float* __restrict__ out) {
    const int b  = blockIdx.z;
    const int bm = blockIdx.y * 64;
    const int bn = blockIdx.x * 128;
    const int wave = threadIdx.x >> 6, lane = threadIdx.x & 63;
    const int lo = lane & 15, hi = lane >> 4;
    const int wn = bn + wave * 64;

    const unsigned short* Ab = wob + (size_t)(bm + lo) * HIDDEN + hi * 8;
    const unsigned short* Bb = attn_t + ((size_t)b * NTOK + wn + lo) * HIDDEN + hi * 8;

    f32x4 acc[4][4];
    #pragma unroll
    for (int mi = 0; mi < 4; ++mi)
        #pragma unroll
        for (int ni = 0; ni < 4; ++ni) acc[mi][ni] = (f32x4){0.f, 0.f, 0.f, 0.f};

    for (int k0 = 0; k0 < HIDDEN; k0 += 32) {
        bf16x8 a[4], bf[4];
        #pragma unroll
        for (int mi = 0; mi < 4; ++mi) a[mi]  = *(const bf16x8*)(Ab + (size_t)mi * 16 * HIDDEN + k0);
        #pragma unroll
        for (int ni = 0; ni < 4; ++ni) bf[ni] = *(const bf16x8*)(Bb + (size_t)ni * 16 * HIDDEN + k0);
        #pragma unroll
        for (int mi = 0; mi < 4; ++mi)
            #pragma unroll
            for (int ni = 0; ni < 4; ++ni)
                acc[mi][ni] = __builtin_amdgcn_mfma_f32_16x16x32_bf16(a[mi], bf[ni], acc[mi][ni], 0, 0, 0);
    }

    __shared__ float OL[2][32][69];
    #pragma unroll
    for (int half = 0; half < 2; ++half) {
        #pragma unroll
        for (int mm = 0; mm < 2; ++mm) {
            const int mi = half * 2 + mm;
            #pragma unroll
            for (int ni = 0; ni < 4; ++ni)
                #pragma unroll
                for (int r = 0; r < 4; ++r)
                    OL[wave][mm * 16 + hi * 4 + r][ni * 16 + lo] = acc[mi][ni][r];
        }
        #pragma unroll
        for (int i = 0; i < 8; ++i) {
            const int flat = i * 64 + lane;
            const int row = flat >> 4, c = flat & 15;
            float4 v = *(float4*)&OL[wave][row][c * 4];
            const int m = bm + half * 32 + row;
            const float bb = b_out[m];
            v.x += bb; v.y += bb; v.z += bb; v.w += bb;
            *(float4*)(out + ((size_t)b * CIN + m) * NTOK + wn + c * 4) = v;
        }
    }
}

// ---------------------------------------------------------------------------
// Launcher. WS layout (65.1 MB peak):
//  xt @0 (4.19M) | wqb @4194304 | wob @4980736 | ss @5242880 (32K) |
//  qs @5308416 (8.39M, attn_t aliased after attn) | ks @13697024 (8.39M) |
//  vb @22085632 (8.39M) | qt @30474240 (33.55M fp32; po bf16 4x8.39M aliased) |
//  pml @64028672 (1.05M)
// ---------------------------------------------------------------------------
extern "C" void kernel_launch(void* const* d_in, const int* in_sizes, int n_in,
                              void* d_out, int out_size, void* d_ws, size_t ws_size,
                              hipStream_t stream) {
    const float* x     = (const float*)d_in[0];
    const float* w_qkv = (const float*)d_in[1];
    const float* w_out = (const float*)d_in[2];
    const float* b_out = (const float*)d_in[3];
    float* out = (float*)d_out;

    char* ws = (char*)d_ws;
    unsigned short* xt  = (unsigned short*)(ws);
    unsigned short* wqb = (unsigned short*)(ws + 4194304);
    unsigned short* wob = (unsigned short*)(ws + 4980736);
    float*          ss  = (float*)(ws + 5242880);
    unsigned short* qs  = (unsigned short*)(ws + 5308416);
    unsigned short* ks  = (unsigned short*)(ws + 13697024);
    unsigned short* vb  = (unsigned short*)(ws + 22085632);
    float*          qt  = (float*)(ws + 30474240);
    unsigned short* po  = (unsigned short*)(ws + 30474240);      // aliases qt (dead)
    unsigned short* attn_t = (unsigned short*)(ws + 5308416);    // aliases qs (dead)
    float*          pml = (float*)(ws + 64028672);

    hipMemsetAsync(ss, 0, 8 * 1024 * sizeof(float), stream);

    cvt_x_kernel<<<dim3(16, 4, 8), 256, 0, stream>>>(x, xt);
    cvt_w_kernel<<<256, 256, 0, stream>>>(w_qkv, w_out, wqb, wob);

    gemm1_kernel<<<dim3(8, 12, 8), 256, 0, stream>>>(wqb, xt, qt, vb, ss);

    scale_cvt_kernel<<<4096, 256, 0, stream>>>(qt, ss, qs, ks);

    attn_mfma_kernel<<<4096, 128, 0, stream>>>(qs, ks, vb, po, pml);

    combine_kernel<<<2048, 256, 0, stream>>>(po, pml, attn_t);

    gemm2_kernel<<<dim3(8, 4, 8), 128, 0, stream>>>(wob, attn_t, b_out, out);
}

// Round 11
// 196.930 us; speedup vs baseline: 1.0554x; 1.0554x over previous
//
#include <hip/hip_runtime.h>
#include <math.h>

#define NHEADS 8
#define DHEAD  64
#define HIDDEN 512     // NHEADS*DHEAD
#define CIN    256
#define NTOK   1024    // 32*32
#define QK_SCALE 10.0f
#define LOG2E 1.44269504088896f
// softmax shift: sim = 10*cos(q,k) <= ~10.1 (bf16 slack); constant shift is exact
#define MSHIFT 10.5f
#define MBIAS  (-MSHIFT * LOG2E)

typedef __bf16 bf16x8 __attribute__((ext_vector_type(8)));
typedef float  f32x4  __attribute__((ext_vector_type(4)));
typedef unsigned u32x4 __attribute__((ext_vector_type(4)));
typedef unsigned short u16x8 __attribute__((ext_vector_type(8)));
typedef unsigned short u16x4 __attribute__((ext_vector_type(4)));

__device__ inline unsigned short f2bf(float f) {
    unsigned u = __builtin_bit_cast(unsigned, f);
    u = (u + 0x7FFFu + ((u >> 16) & 1u)) >> 16;   // RNE
    return (unsigned short)u;
}

// pack two floats -> one u32 of 2 bf16 (RNE; epilogue only)
__device__ inline unsigned pk2(float a, float b) {
    return (unsigned)f2bf(a) | ((unsigned)f2bf(b) << 16);
}

// TRUNCATION pack (3 ops) — attn hot loop; lsum uses the same truncated
// values so the bias cancels in O/l.
__device__ inline unsigned pk2t(float a, float b) {
    return (__builtin_bit_cast(unsigned, a) >> 16) |
           (__builtin_bit_cast(unsigned, b) & 0xFFFF0000u);
}
__device__ inline float trunc_bf(float f) {
    return __builtin_bit_cast(float, __builtin_bit_cast(unsigned, f) & 0xFFFF0000u);
}

__device__ inline float bf2f(unsigned short u) {
    return __builtin_bit_cast(float, (unsigned)u << 16);
}

__device__ inline bf16x8 cvt8(const float* p) {
    float4 a = *(const float4*)p;
    float4 b = *(const float4*)(p + 4);
    u16x8 t;
    t[0] = f2bf(a.x); t[1] = f2bf(a.y); t[2] = f2bf(a.z); t[3] = f2bf(a.w);
    t[4] = f2bf(b.x); t[5] = f2bf(b.y); t[6] = f2bf(b.z); t[7] = f2bf(b.w);
    return __builtin_bit_cast(bf16x8, t);
}

// ---------------------------------------------------------------------------
// x (8,256,1024) fp32 d-major -> xt (8,1024,256) bf16 token-major.
// ---------------------------------------------------------------------------
__global__ __launch_bounds__(256)
void cvt_x_kernel(const float* __restrict__ x, unsigned short* __restrict__ xt) {
    const int b  = blockIdx.z;
    const int c0 = blockIdx.y * 64;
    const int n0 = blockIdx.x * 64;
    const float* src = x + ((size_t)b * CIN + c0) * NTOK + n0;
    unsigned short* dst = xt + ((size_t)b * NTOK + n0) * CIN + c0;

    __shared__ float T[64][65];
    const int t = threadIdx.x;
    {
        const int nq = t & 15, cg = t >> 4;
        #pragma unroll
        for (int rr = 0; rr < 4; ++rr) {
            const int c = cg + rr * 16;
            float4 v = *(const float4*)(src + (size_t)c * NTOK + nq * 4);
            T[c][nq * 4 + 0] = v.x;
            T[c][nq * 4 + 1] = v.y;
            T[c][nq * 4 + 2] = v.z;
            T[c][nq * 4 + 3] = v.w;
        }
    }
    __syncthreads();
    {
        const int n = t >> 2, cq = t & 3;
        alignas(16) unsigned short tmp[16];
        #pragma unroll
        for (int e = 0; e < 16; ++e)
            tmp[e] = f2bf(T[cq * 16 + e][n]);
        *(uint4*)(dst + (size_t)n * CIN + cq * 16)     = *(uint4*)&tmp[0];
        *(uint4*)(dst + (size_t)n * CIN + cq * 16 + 8) = *(uint4*)&tmp[8];
    }
}

// ---------------------------------------------------------------------------
// Weights fp32 -> bf16 (row-major preserved).
// ---------------------------------------------------------------------------
__global__ __launch_bounds__(256)
void cvt_w_kernel(const float* __restrict__ wq, const float* __restrict__ wo,
                  unsigned short* __restrict__ wqb, unsigned short* __restrict__ wob) {
    const size_t i = ((size_t)blockIdx.x * 256 + threadIdx.x) * 8;
    if (i < (size_t)1536 * 256) {
        *(bf16x8*)(wqb + i) = cvt8(wq + i);
    } else {
        const size_t j = i - (size_t)1536 * 256;
        *(bf16x8*)(wob + j) = cvt8(wo + j);
    }
}

// ---------------------------------------------------------------------------
// GEMM1: qkv = w_qkv (1536x256) x x (256x1024) per batch, bf16 MFMA.
// Epilogues: q/k -> token-major fp32 qt + sumsq atomics;
//            v -> bf16 DENSE-TILED vb[bh][jblk][d][64tok], KEY-PERMUTED
//            within 32-token blocks (sigma matches PV's MFMA k-slot layout).
// ---------------------------------------------------------------------------
__global__ __launch_bounds__(256)
void gemm1_kernel(const unsigned short* __restrict__ wqb,
                  const unsigned short* __restrict__ xt,
                  float* __restrict__ qt,
                  unsigned short* __restrict__ vb,
                  float* __restrict__ ss) {
    const int b  = blockIdx.z;
    const int bm = blockIdx.y * 128;
    const int bn = blockIdx.x * 128;
    const int wave = threadIdx.x >> 6, lane = threadIdx.x & 63;
    const int lo = lane & 15, hi = lane >> 4;
    const int wm = bm + (wave >> 1) * 64;
    const int wn = bn + (wave & 1) * 64;

    const unsigned short* Ab = wqb + (size_t)(wm + lo) * CIN + hi * 8;
    const unsigned short* Bb = xt + ((size_t)b * NTOK + wn + lo) * CIN + hi * 8;

    f32x4 acc[4][4];
    #pragma unroll
    for (int mi = 0; mi < 4; ++mi)
        #pragma unroll
        for (int ni = 0; ni < 4; ++ni) acc[mi][ni] = (f32x4){0.f, 0.f, 0.f, 0.f};

    for (int k0 = 0; k0 < CIN; k0 += 32) {
        bf16x8 a[4], bf[4];
        #pragma unroll
        for (int mi = 0; mi < 4; ++mi) a[mi]  = *(const bf16x8*)(Ab + (size_t)mi * 16 * CIN + k0);
        #pragma unroll
        for (int ni = 0; ni < 4; ++ni) bf[ni] = *(const bf16x8*)(Bb + (size_t)ni * 16 * CIN + k0);
        #pragma unroll
        for (int mi = 0; mi < 4; ++mi)
            #pragma unroll
            for (int ni = 0; ni < 4; ++ni)
                acc[mi][ni] = __builtin_amdgcn_mfma_f32_16x16x32_bf16(a[mi], bf[ni], acc[mi][ni], 0, 0, 0);
    }

    __shared__ unsigned short VL[4][32][72];

    if (bm < 1024) {
        const int isK = (wm >= 512) ? 1 : 0;
        const int ch0 = wm & 511;
        const int head = ch0 >> 6;
        float* dst = qt + (((size_t)isK * 64 + b * 8 + head) * NTOK) * DHEAD;
        #pragma unroll
        for (int mi = 0; mi < 4; ++mi) {
            const int d = mi * 16 + hi * 4;
            #pragma unroll
            for (int ni = 0; ni < 4; ++ni) {
                const int n = wn + ni * 16 + lo;
                *(f32x4*)(dst + (size_t)n * DHEAD + d) = acc[mi][ni];
            }
        }
        float p[4][4];
        #pragma unroll
        for (int mi = 0; mi < 4; ++mi)
            #pragma unroll
            for (int r = 0; r < 4; ++r) {
                float s = 0.f;
                #pragma unroll
                for (int ni = 0; ni < 4; ++ni) s += acc[mi][ni][r] * acc[mi][ni][r];
                p[mi][r] = s;
            }
        #pragma unroll
        for (int off = 1; off < 16; off <<= 1)
            #pragma unroll
            for (int mi = 0; mi < 4; ++mi)
                #pragma unroll
                for (int r = 0; r < 4; ++r)
                    p[mi][r] += __shfl_xor(p[mi][r], off, 64);
        if (lo == 0) {
            #pragma unroll
            for (int mi = 0; mi < 4; ++mi)
                #pragma unroll
                for (int r = 0; r < 4; ++r)
                    atomicAdd(&ss[(size_t)b * 1024 + isK * 512 + ch0 + mi * 16 + hi * 4 + r], p[mi][r]);
        }
    } else {
        const int ch0 = wm - 1024;                 // 0..511, multiple of 64
        const int h = ch0 >> 6;
        unsigned short* tile = vb + (((size_t)b * 8 + h) * 16 + (wn >> 6)) * 4096;
        #pragma unroll
        for (int half = 0; half < 2; ++half) {
            #pragma unroll
            for (int mm = 0; mm < 2; ++mm) {
                const int mi = half * 2 + mm;
                #pragma unroll
                for (int ni = 0; ni < 4; ++ni)
                    #pragma unroll
                    for (int r = 0; r < 4; ++r)
                        VL[wave][mm * 16 + hi * 4 + r][ni * 16 + lo] = f2bf(acc[mi][ni][r]);
            }
            // wave-synchronous readback WITH key-permutation sigma -> dense tile
            #pragma unroll
            for (int i = 0; i < 4; ++i) {
                const int flat = i * 64 + lane;
                const int row = flat >> 3, c = flat & 7;
                const int tb = c >> 2, hg = c & 3;
                const uint2 vlo = *(uint2*)&VL[wave][row][tb * 32 + hg * 4];
                const uint2 vhi = *(uint2*)&VL[wave][row][tb * 32 + hg * 4 + 16];
                uint4 v = make_uint4(vlo.x, vlo.y, vhi.x, vhi.y);
                const int d = half * 32 + row;
                *(uint4*)(tile + (size_t)d * 64 + c * 8) = v;
            }
        }
    }
}

// ---------------------------------------------------------------------------
// qt fp32 [isK][bh][n][d] -> qs/ks bf16 [bh][n][d], scaled by rsqrt(ss) (x10 q).
// ---------------------------------------------------------------------------
__global__ __launch_bounds__(256)
void scale_cvt_kernel(const float* __restrict__ qt, const float* __restrict__ ss,
                      unsigned short* __restrict__ qs, unsigned short* __restrict__ ks) {
    const size_t idx = ((size_t)blockIdx.x * 256 + threadIdx.x) * 8;
    const size_t half = (size_t)64 * NTOK * DHEAD;
    const int isK = idx >= half;
    const size_t rem = idx - (size_t)isK * half;
    const int bh = (int)(rem >> 16);
    const int d0 = (int)(rem & 63);
    const int b  = bh >> 3;
    const int ch = isK * 512 + (bh & 7) * 64 + d0;
    const float scl = isK ? 1.0f : QK_SCALE;

    const float* ip = qt + idx;
    float4 v0 = *(const float4*)ip;
    float4 v1 = *(const float4*)(ip + 4);
    float4 q0 = *(const float4*)(ss + (size_t)b * 1024 + ch);
    float4 q1 = *(const float4*)(ss + (size_t)b * 1024 + ch + 4);
    float4 s0, s1;
    s0.x = 1.0f / fmaxf(sqrtf(q0.x), 1e-12f); s0.y = 1.0f / fmaxf(sqrtf(q0.y), 1e-12f);
    s0.z = 1.0f / fmaxf(sqrtf(q0.z), 1e-12f); s0.w = 1.0f / fmaxf(sqrtf(q0.w), 1e-12f);
    s1.x = 1.0f / fmaxf(sqrtf(q1.x), 1e-12f); s1.y = 1.0f / fmaxf(sqrtf(q1.y), 1e-12f);
    s1.z = 1.0f / fmaxf(sqrtf(q1.z), 1e-12f); s1.w = 1.0f / fmaxf(sqrtf(q1.w), 1e-12f);
    u16x8 t;
    t[0] = f2bf(v0.x * s0.x * scl); t[1] = f2bf(v0.y * s0.y * scl);
    t[2] = f2bf(v0.z * s0.z * scl); t[3] = f2bf(v0.w * s0.w * scl);
    t[4] = f2bf(v1.x * s1.x * scl); t[5] = f2bf(v1.y * s1.y * scl);
    t[6] = f2bf(v1.z * s1.z * scl); t[7] = f2bf(v1.w * s1.w * scl);
    *(u16x8*)((isK ? ks : qs) + rem) = t;
}

// ---------------------------------------------------------------------------
// MFMA flash attention, NO split-K (16 jt per wave), fixed shift M=10.5.
// SWAPPED operands; P lane-local in registers; PV k-permutation pre-baked
// into vb's dense tiles. NO LDS, NO barriers, NO in-loop cross-lane ops.
// Epilogue applies 1/l and writes attn_t bf16 token-major [b][n][512].
// ---------------------------------------------------------------------------
__global__ __launch_bounds__(128)
void attn_mfma_kernel(const unsigned short* __restrict__ qs,
                      const unsigned short* __restrict__ ks,
                      const unsigned short* __restrict__ vb,
                      unsigned short* __restrict__ attn_t) {
    const int hw = blockIdx.x;                    // 1024 blocks
    const int virt = (hw & 7) * 128 + (hw >> 3);  // XCD-chunked: 8 bh per XCD
    const int bh = virt >> 4;
    const int it = virt & 15;
    const int b = bh >> 3, h = bh & 7;

    const int lane = threadIdx.x & 63;
    const int wave = threadIdx.x >> 6;            // 0..1
    const int lo = lane & 15;
    const int hi = lane >> 4;
    const int iw = it * 64 + wave * 32;

    const unsigned short* qbh = qs + (size_t)bh * NTOK * DHEAD;
    const unsigned short* kbh = ks + (size_t)bh * NTOK * DHEAD;
    const unsigned short* vbh = vb + (size_t)bh * 16 * 4096;   // dense tiles

    // Q fragments (once): frag f covers q-rows iw+f*16+lo
    bf16x8 aQ[2][2];
    #pragma unroll
    for (int f = 0; f < 2; ++f) {
        const unsigned short* qp = qbh + (size_t)(iw + f * 16 + lo) * DHEAD + hi * 8;
        aQ[f][0] = *(const bf16x8*)qp;
        aQ[f][1] = *(const bf16x8*)(qp + 32);
    }

    float lsum4[2][4];
    #pragma unroll
    for (int f = 0; f < 2; ++f)
        #pragma unroll
        for (int r = 0; r < 4; ++r) lsum4[f][r] = 0.0f;
    f32x4 acc[2][4];
    #pragma unroll
    for (int f = 0; f < 2; ++f)
        #pragma unroll
        for (int ds = 0; ds < 4; ++ds) acc[f][ds] = (f32x4){0.f, 0.f, 0.f, 0.f};

    #pragma unroll 2
    for (int jt = 0; jt < 16; ++jt) {
        const int j0 = jt * 64;

        // --- V A-fragments from the dense 8KB tile (perm pre-baked)
        bf16x8 bV[4][2];
        {
            const unsigned short* vt = vbh + (size_t)jt * 4096;
            #pragma unroll
            for (int ds = 0; ds < 4; ++ds) {
                const unsigned short* vp = vt + (ds * 16 + lo) * 64 + hi * 8;
                bV[ds][0] = *(const bf16x8*)vp;
                bV[ds][1] = *(const bf16x8*)(vp + 32);
            }
        }

        // --- K fragments
        bf16x8 bK[4][2];
        #pragma unroll
        for (int jj = 0; jj < 4; ++jj) {
            const unsigned short* kp = kbh + (size_t)(j0 + jj * 16 + lo) * DHEAD + hi * 8;
            bK[jj][0] = *(const bf16x8*)kp;
            bK[jj][1] = *(const bf16x8*)(kp + 32);
        }

        // --- QK^T swapped: s[f][jj][r] = P[q=lo][k = jj*16 + hi*4 + r]
        f32x4 s[2][4];
        __builtin_amdgcn_s_setprio(1);
        #pragma unroll
        for (int jj = 0; jj < 4; ++jj)
            #pragma unroll
            for (int f = 0; f < 2; ++f) {
                f32x4 c = (f32x4){0.f, 0.f, 0.f, 0.f};
                c = __builtin_amdgcn_mfma_f32_16x16x32_bf16(bK[jj][0], aQ[f][0], c, 0, 0, 0);
                c = __builtin_amdgcn_mfma_f32_16x16x32_bf16(bK[jj][1], aQ[f][1], c, 0, 0, 0);
                s[f][jj] = c;
            }
        __builtin_amdgcn_s_setprio(0);

        // --- p = exp(s - 10.5); truncated lsum; truncation pack (3 ops/pair)
        unsigned pw[2][2][4];   // [f][t][word]
        #pragma unroll
        for (int f = 0; f < 2; ++f) {
            #pragma unroll
            for (int jj = 0; jj < 4; ++jj)
                #pragma unroll
                for (int r = 0; r < 4; ++r) {
                    const float p = __builtin_amdgcn_exp2f(fmaf(s[f][jj][r], LOG2E, MBIAS));
                    s[f][jj][r] = p;
                    lsum4[f][r] += trunc_bf(p);
                }
            #pragma unroll
            for (int t = 0; t < 2; ++t) {
                pw[f][t][0] = pk2t(s[f][2 * t][0],     s[f][2 * t][1]);
                pw[f][t][1] = pk2t(s[f][2 * t][2],     s[f][2 * t][3]);
                pw[f][t][2] = pk2t(s[f][2 * t + 1][0], s[f][2 * t + 1][1]);
                pw[f][t][3] = pk2t(s[f][2 * t + 1][2], s[f][2 * t + 1][3]);
            }
        }

        // --- PV swapped: acc[f][ds] += V-frag x P-frag
        __builtin_amdgcn_s_setprio(1);
        #pragma unroll
        for (int ds = 0; ds < 4; ++ds)
            #pragma unroll
            for (int f = 0; f < 2; ++f)
                #pragma unroll
                for (int t = 0; t < 2; ++t) {
                    const bf16x8 bp = __builtin_bit_cast(bf16x8,
                        (u32x4){pw[f][t][0], pw[f][t][1], pw[f][t][2], pw[f][t][3]});
                    acc[f][ds] = __builtin_amdgcn_mfma_f32_16x16x32_bf16(bV[ds][t], bp, acc[f][ds], 0, 0, 0);
                }
        __builtin_amdgcn_s_setprio(0);
    }

    // --- fold 4 lsum chains, then 2 cross-lane rounds (once per kernel)
    float lsum[2];
    #pragma unroll
    for (int f = 0; f < 2; ++f) {
        lsum[f] = (lsum4[f][0] + lsum4[f][1]) + (lsum4[f][2] + lsum4[f][3]);
        lsum[f] += __shfl_xor(lsum[f], 16, 64);
        lsum[f] += __shfl_xor(lsum[f], 32, 64);
    }

    // --- epilogue: 1/l + direct stores, attn_t[b][n=iw+f*16+lo][h*64 + d]
    unsigned short* at = attn_t + ((size_t)b * NTOK + iw) * HIDDEN + h * DHEAD;
    #pragma unroll
    for (int f = 0; f < 2; ++f) {
        const float inv = 1.0f / lsum[f];
        #pragma unroll
        for (int ds = 0; ds < 4; ++ds) {
            uint2 w;
            w.x = pk2(acc[f][ds][0] * inv, acc[f][ds][1] * inv);
            w.y = pk2(acc[f][ds][2] * inv, acc[f][ds][3] * inv);
            *(uint2*)(at + (size_t)(f * 16 + lo) * HIDDEN + ds * 16 + hi * 4) = w;
        }
    }
}

// ---------------------------------------------------------------------------
// GEMM2: out = w_out (256x512) x attn_t^T + bias, bf16 MFMA.
// ---------------------------------------------------------------------------
__global__ __launch_bounds__(128)
void gemm2_kernel(const unsigned short* __restrict__ wob,
                  const unsigned short* __restrict__ attn_t,
                  const float* __restrict__ b_out,
                  float* __restrict__ out) {
    const int b  = blockIdx.z;
    const int bm = blockIdx.y * 64;
    const int bn = blockIdx.x * 128;
    const int wave = threadIdx.x >> 6, lane = threadIdx.x & 63;
    const int lo = lane & 15, hi = lane >> 4;
    const int wn = bn + wave * 64;

    const unsigned short* Ab = wob + (size_t)(bm + lo) * HIDDEN + hi * 8;
    const unsigned short* Bb = attn_t + ((size_t)b * NTOK + wn + lo) * HIDDEN + hi * 8;

    f32x4 acc[4][4];
    #pragma unroll
    for (int mi = 0; mi < 4; ++mi)
        #pragma unroll
        for (int ni = 0; ni < 4; ++ni) acc[mi][ni] = (f32x4){0.f, 0.f, 0.f, 0.f};

    for (int k0 = 0; k0 < HIDDEN; k0 += 32) {
        bf16x8 a[4], bf[4];
        #pragma unroll
        for (int mi = 0; mi < 4; ++mi) a[mi]  = *(const bf16x8*)(Ab + (size_t)mi * 16 * HIDDEN + k0);
        #pragma unroll
        for (int ni = 0; ni < 4; ++ni) bf[ni] = *(const bf16x8*)(Bb + (size_t)ni * 16 * HIDDEN + k0);
        #pragma unroll
        for (int mi = 0; mi < 4; ++mi)
            #pragma unroll
            for (int ni = 0; ni < 4; ++ni)
                acc[mi][ni] = __builtin_amdgcn_mfma_f32_16x16x32_bf16(a[mi], bf[ni], acc[mi][ni], 0, 0, 0);
    }

    __shared__ float OL[2][32][69];
    #pragma unroll
    for (int half = 0; half < 2; ++half) {
        #pragma unroll
        for (int mm = 0; mm < 2; ++mm) {
            const int mi = half * 2 + mm;
            #pragma unroll
            for (int ni = 0; ni < 4; ++ni)
                #pragma unroll
                for (int r = 0; r < 4; ++r)
                    OL[wave][mm * 16 + hi * 4 + r][ni * 16 + lo] = acc[mi][ni][r];
        }
        #pragma unroll
        for (int i = 0; i < 8; ++i) {
            const int flat = i * 64 + lane;
            const int row = flat >> 4, c = flat & 15;
            float4 v = *(float4*)&OL[wave][row][c * 4];
            const int m = bm + half * 32 + row;
            const float bb = b_out[m];
            v.x += bb; v.y += bb; v.z += bb; v.w += bb;
            *(float4*)(out + ((size_t)b * CIN + m) * NTOK + wn + c * 4) = v;
        }
    }
}

// ---------------------------------------------------------------------------
// Launcher. WS layout (64.0 MB peak):
//  xt @0 (4.19M) | wqb @4194304 | wob @4980736 | ss @5242880 (32K) |
//  qs @5308416 (8.39M) | ks @13697024 (8.39M) | vb @22085632 (8.39M) |
//  qt @30474240 (33.55M fp32; attn_t bf16 8.39M aliased after scale_cvt)
// ---------------------------------------------------------------------------
extern "C" void kernel_launch(void* const* d_in, const int* in_sizes, int n_in,
                              void* d_out, int out_size, void* d_ws, size_t ws_size,
                              hipStream_t stream) {
    const float* x     = (const float*)d_in[0];
    const float* w_qkv = (const float*)d_in[1];
    const float* w_out = (const float*)d_in[2];
    const float* b_out = (const float*)d_in[3];
    float* out = (float*)d_out;

    char* ws = (char*)d_ws;
    unsigned short* xt  = (unsigned short*)(ws);
    unsigned short* wqb = (unsigned short*)(ws + 4194304);
    unsigned short* wob = (unsigned short*)(ws + 4980736);
    float*          ss  = (float*)(ws + 5242880);
    unsigned short* qs  = (unsigned short*)(ws + 5308416);
    unsigned short* ks  = (unsigned short*)(ws + 13697024);
    unsigned short* vb  = (unsigned short*)(ws + 22085632);
    float*          qt  = (float*)(ws + 30474240);
    unsigned short* attn_t = (unsigned short*)(ws + 30474240);   // aliases qt (dead after scale_cvt)

    hipMemsetAsync(ss, 0, 8 * 1024 * sizeof(float), stream);

    cvt_x_kernel<<<dim3(16, 4, 8), 256, 0, stream>>>(x, xt);
    cvt_w_kernel<<<256, 256, 0, stream>>>(w_qkv, w_out, wqb, wob);

    gemm1_kernel<<<dim3(8, 12, 8), 256, 0, stream>>>(wqb, xt, qt, vb, ss);

    scale_cvt_kernel<<<4096, 256, 0, stream>>>(qt, ss, qs, ks);

    attn_mfma_kernel<<<1024, 128, 0, stream>>>(qs, ks, vb, attn_t);

    gemm2_kernel<<<dim3(8, 4, 8), 128, 0, stream>>>(wob, attn_t, b_out, out);
}

// Round 12
// 179.342 us; speedup vs baseline: 1.1589x; 1.0981x over previous
//
#include <hip/hip_runtime.h>
#include <math.h>

#define NHEADS 8
#define DHEAD  64
#define HIDDEN 512     // NHEADS*DHEAD
#define CIN    256
#define NTOK   1024    // 32*32
#define QK_SCALE 10.0f
#define LOG2E 1.44269504088896f
// fixed softmax shift: ANY constant shift is mathematically exact (shift-
// invariance); 10.5 keeps exp args in a comfortable fp32/bf16 range.
#define MSHIFT 10.5f
#define MBIAS  (-MSHIFT * LOG2E)

typedef __bf16 bf16x8 __attribute__((ext_vector_type(8)));
typedef float  f32x4  __attribute__((ext_vector_type(4)));
typedef unsigned u32x4 __attribute__((ext_vector_type(4)));
typedef unsigned short u16x8 __attribute__((ext_vector_type(8)));

__device__ inline unsigned short f2bf(float f) {
    unsigned u = __builtin_bit_cast(unsigned, f);
    u = (u + 0x7FFFu + ((u >> 16) & 1u)) >> 16;   // RNE
    return (unsigned short)u;
}

// pack two floats -> one u32 of 2 bf16 (RNE)
__device__ inline unsigned pk2(float a, float b) {
    return (unsigned)f2bf(a) | ((unsigned)f2bf(b) << 16);
}

// TRUNCATION pack (3 ops) — attn hot loop; the lsum MFMA consumes the SAME
// truncated bits, so the O/l ratio is unbiased.
__device__ inline unsigned pk2t(float a, float b) {
    return (__builtin_bit_cast(unsigned, a) >> 16) |
           (__builtin_bit_cast(unsigned, b) & 0xFFFF0000u);
}

__device__ inline float bf2f(unsigned short u) {
    return __builtin_bit_cast(float, (unsigned)u << 16);
}

__device__ inline bf16x8 cvt8(const float* p) {
    float4 a = *(const float4*)p;
    float4 b = *(const float4*)(p + 4);
    u16x8 t;
    t[0] = f2bf(a.x); t[1] = f2bf(a.y); t[2] = f2bf(a.z); t[3] = f2bf(a.w);
    t[4] = f2bf(b.x); t[5] = f2bf(b.y); t[6] = f2bf(b.z); t[7] = f2bf(b.w);
    return __builtin_bit_cast(bf16x8, t);
}

// scale 8 bf16 lanes-worth by 8 f32 factors, repack (RNE; prologue-only)
__device__ inline bf16x8 scale8(bf16x8 v, const float* s) {
    u16x8 u = __builtin_bit_cast(u16x8, v);
    u32x4 r;
    r[0] = pk2(bf2f(u[0]) * s[0], bf2f(u[1]) * s[1]);
    r[1] = pk2(bf2f(u[2]) * s[2], bf2f(u[3]) * s[3]);
    r[2] = pk2(bf2f(u[4]) * s[4], bf2f(u[5]) * s[5]);
    r[3] = pk2(bf2f(u[6]) * s[6], bf2f(u[7]) * s[7]);
    return __builtin_bit_cast(bf16x8, r);
}

// ---------------------------------------------------------------------------
// prep: blocks 0..511  -> x (8,256,1024) fp32 -> xt (8,1024,256) bf16
//       blocks 512..767 -> weights fp32 -> bf16
// ---------------------------------------------------------------------------
__global__ __launch_bounds__(256)
void prep_kernel(const float* __restrict__ x, const float* __restrict__ wq,
                 const float* __restrict__ wo,
                 unsigned short* __restrict__ xt, unsigned short* __restrict__ wqb,
                 unsigned short* __restrict__ wob) {
    __shared__ float T[64][65];
    const int blk = blockIdx.x;
    const int t = threadIdx.x;
    if (blk < 512) {
        const int n0 = (blk & 15) * 64;
        const int c0 = ((blk >> 4) & 3) * 64;
        const int b  = blk >> 6;
        const float* src = x + ((size_t)b * CIN + c0) * NTOK + n0;
        unsigned short* dst = xt + ((size_t)b * NTOK + n0) * CIN + c0;
        {
            const int nq = t & 15, cg = t >> 4;
            #pragma unroll
            for (int rr = 0; rr < 4; ++rr) {
                const int c = cg + rr * 16;
                float4 v = *(const float4*)(src + (size_t)c * NTOK + nq * 4);
                T[c][nq * 4 + 0] = v.x;
                T[c][nq * 4 + 1] = v.y;
                T[c][nq * 4 + 2] = v.z;
                T[c][nq * 4 + 3] = v.w;
            }
        }
        __syncthreads();
        {
            const int n = t >> 2, cq = t & 3;
            alignas(16) unsigned short tmp[16];
            #pragma unroll
            for (int e = 0; e < 16; ++e)
                tmp[e] = f2bf(T[cq * 16 + e][n]);
            *(uint4*)(dst + (size_t)n * CIN + cq * 16)     = *(uint4*)&tmp[0];
            *(uint4*)(dst + (size_t)n * CIN + cq * 16 + 8) = *(uint4*)&tmp[8];
        }
    } else {
        const size_t i = ((size_t)(blk - 512) * 256 + t) * 8;
        if (i < (size_t)1536 * 256) {
            *(bf16x8*)(wqb + i) = cvt8(wq + i);
        } else {
            const size_t j = i - (size_t)1536 * 256;
            *(bf16x8*)(wob + j) = cvt8(wo + j);
        }
    }
}

// ---------------------------------------------------------------------------
// GEMM1: qkv = w_qkv (1536x256) x x (256x1024) per batch, bf16 MFMA.
// Epilogues: q/k -> token-major bf16 qk[isK][bh][n][d] (UNSCALED) + sumsq
//            atomics; v -> bf16 DENSE-TILED vb[bh][jblk][d][64tok],
//            KEY-PERMUTED within 32-token blocks (sigma matches PV k-slots).
// ---------------------------------------------------------------------------
__global__ __launch_bounds__(256)
void gemm1_kernel(const unsigned short* __restrict__ wqb,
                  const unsigned short* __restrict__ xt,
                  unsigned short* __restrict__ qk,
                  unsigned short* __restrict__ vb,
                  float* __restrict__ ss) {
    const int b  = blockIdx.z;
    const int bm = blockIdx.y * 128;
    const int bn = blockIdx.x * 128;
    const int wave = threadIdx.x >> 6, lane = threadIdx.x & 63;
    const int lo = lane & 15, hi = lane >> 4;
    const int wm = bm + (wave >> 1) * 64;
    const int wn = bn + (wave & 1) * 64;

    const unsigned short* Ab = wqb + (size_t)(wm + lo) * CIN + hi * 8;
    const unsigned short* Bb = xt + ((size_t)b * NTOK + wn + lo) * CIN + hi * 8;

    f32x4 acc[4][4];
    #pragma unroll
    for (int mi = 0; mi < 4; ++mi)
        #pragma unroll
        for (int ni = 0; ni < 4; ++ni) acc[mi][ni] = (f32x4){0.f, 0.f, 0.f, 0.f};

    for (int k0 = 0; k0 < CIN; k0 += 32) {
        bf16x8 a[4], bf[4];
        #pragma unroll
        for (int mi = 0; mi < 4; ++mi) a[mi]  = *(const bf16x8*)(Ab + (size_t)mi * 16 * CIN + k0);
        #pragma unroll
        for (int ni = 0; ni < 4; ++ni) bf[ni] = *(const bf16x8*)(Bb + (size_t)ni * 16 * CIN + k0);
        #pragma unroll
        for (int mi = 0; mi < 4; ++mi)
            #pragma unroll
            for (int ni = 0; ni < 4; ++ni)
                acc[mi][ni] = __builtin_amdgcn_mfma_f32_16x16x32_bf16(a[mi], bf[ni], acc[mi][ni], 0, 0, 0);
    }

    __shared__ unsigned short VL[4][32][72];

    if (bm < 1024) {
        const int isK = (wm >= 512) ? 1 : 0;
        const int ch0 = wm & 511;
        const int head = ch0 >> 6;
        unsigned short* dst = qk + (((size_t)(isK * 64 + b * 8 + head)) * NTOK) * DHEAD;
        #pragma unroll
        for (int mi = 0; mi < 4; ++mi) {
            const int d = mi * 16 + hi * 4;
            #pragma unroll
            for (int ni = 0; ni < 4; ++ni) {
                const int n = wn + ni * 16 + lo;
                uint2 wv;
                wv.x = pk2(acc[mi][ni][0], acc[mi][ni][1]);
                wv.y = pk2(acc[mi][ni][2], acc[mi][ni][3]);
                *(uint2*)(dst + (size_t)n * DHEAD + d) = wv;
            }
        }
        float p[4][4];
        #pragma unroll
        for (int mi = 0; mi < 4; ++mi)
            #pragma unroll
            for (int r = 0; r < 4; ++r) {
                float s = 0.f;
                #pragma unroll
                for (int ni = 0; ni < 4; ++ni) s += acc[mi][ni][r] * acc[mi][ni][r];
                p[mi][r] = s;
            }
        #pragma unroll
        for (int off = 1; off < 16; off <<= 1)
            #pragma unroll
            for (int mi = 0; mi < 4; ++mi)
                #pragma unroll
                for (int r = 0; r < 4; ++r)
                    p[mi][r] += __shfl_xor(p[mi][r], off, 64);
        if (lo == 0) {
            #pragma unroll
            for (int mi = 0; mi < 4; ++mi)
                #pragma unroll
                for (int r = 0; r < 4; ++r)
                    atomicAdd(&ss[(size_t)b * 1024 + isK * 512 + ch0 + mi * 16 + hi * 4 + r], p[mi][r]);
        }
    } else {
        const int ch0 = wm - 1024;                 // 0..511, multiple of 64
        const int h = ch0 >> 6;
        unsigned short* tile = vb + (((size_t)b * 8 + h) * 16 + (wn >> 6)) * 4096;
        #pragma unroll
        for (int half = 0; half < 2; ++half) {
            #pragma unroll
            for (int mm = 0; mm < 2; ++mm) {
                const int mi = half * 2 + mm;
                #pragma unroll
                for (int ni = 0; ni < 4; ++ni)
                    #pragma unroll
                    for (int r = 0; r < 4; ++r)
                        VL[wave][mm * 16 + hi * 4 + r][ni * 16 + lo] = f2bf(acc[mi][ni][r]);
            }
            // wave-synchronous readback WITH key-permutation sigma -> dense tile
            #pragma unroll
            for (int i = 0; i < 4; ++i) {
                const int flat = i * 64 + lane;
                const int row = flat >> 3, c = flat & 7;
                const int tb = c >> 2, hg = c & 3;
                const uint2 vlo = *(uint2*)&VL[wave][row][tb * 32 + hg * 4];
                const uint2 vhi = *(uint2*)&VL[wave][row][tb * 32 + hg * 4 + 16];
                uint4 v = make_uint4(vlo.x, vlo.y, vhi.x, vhi.y);
                const int d = half * 32 + row;
                *(uint4*)(tile + (size_t)d * 64 + c * 8) = v;
            }
        }
    }
}

// ---------------------------------------------------------------------------
// wnorm: w[b*512 + ch] = 10 / (max(||q_ch||,eps) * max(||k_ch||,eps))
// ---------------------------------------------------------------------------
__global__ __launch_bounds__(256)
void wnorm_kernel(const float* __restrict__ ss, float* __restrict__ wsc) {
    const int i = blockIdx.x * 256 + threadIdx.x;   // 0..4095
    const int b = i >> 9, ch = i & 511;
    const float nq = fmaxf(sqrtf(ss[(size_t)b * 1024 + ch]),       1e-12f);
    const float nk = fmaxf(sqrtf(ss[(size_t)b * 1024 + 512 + ch]), 1e-12f);
    wsc[i] = QK_SCALE / (nq * nk);
}

// ---------------------------------------------------------------------------
// MFMA flash attention. Scale w[d]=10*qn[d]*kn[d] folded into Q fragments
// ONLY (per-d scales commute into either QK operand); K is raw bf16.
// Fixed shift M=10.5; swapped operands; P lane-local; PV k-permutation
// pre-baked in vb dense tiles. lsum computed by mfma(ones, P) — consumes
// the exact packed P bits, so numerator/denominator are consistent and no
// cross-lane reduction is needed at all.
// NO LDS, NO barriers, NO cross-lane ops anywhere.
// ---------------------------------------------------------------------------
__global__ __launch_bounds__(128)
void attn_mfma_kernel(const unsigned short* __restrict__ qk,
                      const unsigned short* __restrict__ vb,
                      const float* __restrict__ wsc,
                      unsigned short* __restrict__ attn_t) {
    const int hw = blockIdx.x;                    // 1024 blocks
    const int virt = (hw & 7) * 128 + (hw >> 3);  // XCD-chunked: 8 bh per XCD
    const int bh = virt >> 4;
    const int it = virt & 15;
    const int b = bh >> 3, h = bh & 7;

    const int lane = threadIdx.x & 63;
    const int wave = threadIdx.x >> 6;            // 0..1
    const int lo = lane & 15;
    const int hi = lane >> 4;
    const int iw = it * 64 + wave * 32;

    const unsigned short* qbh = qk + (size_t)bh * NTOK * DHEAD;
    const unsigned short* kbh = qk + (size_t)(64 + bh) * NTOK * DHEAD;
    const unsigned short* vbh = vb + (size_t)bh * 16 * 4096;   // dense tiles

    // per-d scale factors for this lane's fragment slots
    float wa[8], wb[8];
    {
        const float* wp = wsc + (size_t)b * 512 + h * DHEAD;
        *(float4*)&wa[0] = *(const float4*)(wp + hi * 8);
        *(float4*)&wa[4] = *(const float4*)(wp + hi * 8 + 4);
        *(float4*)&wb[0] = *(const float4*)(wp + 32 + hi * 8);
        *(float4*)&wb[4] = *(const float4*)(wp + 32 + hi * 8 + 4);
    }

    // Q fragments (once), scaled by w[d]
    bf16x8 aQ[2][2];
    #pragma unroll
    for (int f = 0; f < 2; ++f) {
        const unsigned short* qp = qbh + (size_t)(iw + f * 16 + lo) * DHEAD + hi * 8;
        aQ[f][0] = scale8(*(const bf16x8*)qp,        wa);
        aQ[f][1] = scale8(*(const bf16x8*)(qp + 32), wb);
    }

    const bf16x8 ones = __builtin_bit_cast(bf16x8,
        (u32x4){0x3F803F80u, 0x3F803F80u, 0x3F803F80u, 0x3F803F80u});

    f32x4 acc[2][4];
    f32x4 accl[2];
    #pragma unroll
    for (int f = 0; f < 2; ++f) {
        accl[f] = (f32x4){0.f, 0.f, 0.f, 0.f};
        #pragma unroll
        for (int ds = 0; ds < 4; ++ds) acc[f][ds] = (f32x4){0.f, 0.f, 0.f, 0.f};
    }

    #pragma unroll 2
    for (int jt = 0; jt < 16; ++jt) {
        const int j0 = jt * 64;

        // --- V A-fragments from the dense 8KB tile (perm pre-baked)
        bf16x8 bV[4][2];
        {
            const unsigned short* vt = vbh + (size_t)jt * 4096;
            #pragma unroll
            for (int ds = 0; ds < 4; ++ds) {
                const unsigned short* vp = vt + (ds * 16 + lo) * 64 + hi * 8;
                bV[ds][0] = *(const bf16x8*)vp;
                bV[ds][1] = *(const bf16x8*)(vp + 32);
            }
        }

        // --- K fragments (raw, unscaled)
        bf16x8 bK[4][2];
        #pragma unroll
        for (int jj = 0; jj < 4; ++jj) {
            const unsigned short* kp = kbh + (size_t)(j0 + jj * 16 + lo) * DHEAD + hi * 8;
            bK[jj][0] = *(const bf16x8*)kp;
            bK[jj][1] = *(const bf16x8*)(kp + 32);
        }

        // --- QK^T swapped: s[f][jj][r] = sim[q=lo][k = jj*16 + hi*4 + r]
        f32x4 s[2][4];
        __builtin_amdgcn_s_setprio(1);
        #pragma unroll
        for (int jj = 0; jj < 4; ++jj)
            #pragma unroll
            for (int f = 0; f < 2; ++f) {
                f32x4 c = (f32x4){0.f, 0.f, 0.f, 0.f};
                c = __builtin_amdgcn_mfma_f32_16x16x32_bf16(bK[jj][0], aQ[f][0], c, 0, 0, 0);
                c = __builtin_amdgcn_mfma_f32_16x16x32_bf16(bK[jj][1], aQ[f][1], c, 0, 0, 0);
                s[f][jj] = c;
            }
        __builtin_amdgcn_s_setprio(0);

        // --- p = exp(s - 10.5); truncation pack (3 ops/pair); no reductions
        bf16x8 bp[2][2];
        #pragma unroll
        for (int f = 0; f < 2; ++f) {
            #pragma unroll
            for (int jj = 0; jj < 4; ++jj)
                #pragma unroll
                for (int r = 0; r < 4; ++r)
                    s[f][jj][r] = __builtin_amdgcn_exp2f(fmaf(s[f][jj][r], LOG2E, MBIAS));
            #pragma unroll
            for (int t = 0; t < 2; ++t) {
                u32x4 pw;
                pw[0] = pk2t(s[f][2 * t][0],     s[f][2 * t][1]);
                pw[1] = pk2t(s[f][2 * t][2],     s[f][2 * t][3]);
                pw[2] = pk2t(s[f][2 * t + 1][0], s[f][2 * t + 1][1]);
                pw[3] = pk2t(s[f][2 * t + 1][2], s[f][2 * t + 1][3]);
                bp[f][t] = __builtin_bit_cast(bf16x8, pw);
            }
        }

        // --- PV swapped + lsum rows via ones-MFMA (same P bits)
        __builtin_amdgcn_s_setprio(1);
        #pragma unroll
        for (int f = 0; f < 2; ++f)
            #pragma unroll
            for (int t = 0; t < 2; ++t) {
                accl[f] = __builtin_amdgcn_mfma_f32_16x16x32_bf16(ones, bp[f][t], accl[f], 0, 0, 0);
                #pragma unroll
                for (int ds = 0; ds < 4; ++ds)
                    acc[f][ds] = __builtin_amdgcn_mfma_f32_16x16x32_bf16(bV[ds][t], bp[f][t], acc[f][ds], 0, 0, 0);
            }
        __builtin_amdgcn_s_setprio(0);
    }

    // --- epilogue: 1/l + direct stores, attn_t[b][n=iw+f*16+lo][h*64 + d]
    unsigned short* at = attn_t + ((size_t)b * NTOK + iw) * HIDDEN + h * DHEAD;
    #pragma unroll
    for (int f = 0; f < 2; ++f) {
        const float inv = 1.0f / accl[f][0];   // full sum over all 1024 keys
        #pragma unroll
        for (int ds = 0; ds < 4; ++ds) {
            uint2 w;
            w.x = pk2(acc[f][ds][0] * inv, acc[f][ds][1] * inv);
            w.y = pk2(acc[f][ds][2] * inv, acc[f][ds][3] * inv);
            *(uint2*)(at + (size_t)(f * 16 + lo) * HIDDEN + ds * 16 + hi * 4) = w;
        }
    }
}

// ---------------------------------------------------------------------------
// GEMM2: out = w_out (256x512) x attn_t^T + bias, bf16 MFMA.
// ---------------------------------------------------------------------------
__global__ __launch_bounds__(128)
void gemm2_kernel(const unsigned short* __restrict__ wob,
                  const unsigned short* __restrict__ attn_t,
                  const float* __restrict__ b_out,
                  float* __restrict__ out) {
    const int b  = blockIdx.z;
    const int bm = blockIdx.y * 64;
    const int bn = blockIdx.x * 128;
    const int wave = threadIdx.x >> 6, lane = threadIdx.x & 63;
    const int lo = lane & 15, hi = lane >> 4;
    const int wn = bn + wave * 64;

    const unsigned short* Ab = wob + (size_t)(bm + lo) * HIDDEN + hi * 8;
    const unsigned short* Bb = attn_t + ((size_t)b * NTOK + wn + lo) * HIDDEN + hi * 8;

    f32x4 acc[4][4];
    #pragma unroll
    for (int mi = 0; mi < 4; ++mi)
        #pragma unroll
        for (int ni = 0; ni < 4; ++ni) acc[mi][ni] = (f32x4){0.f, 0.f, 0.f, 0.f};

    for (int k0 = 0; k0 < HIDDEN; k0 += 32) {
        bf16x8 a[4], bf[4];
        #pragma unroll
        for (int mi = 0; mi < 4; ++mi) a[mi]  = *(const bf16x8*)(Ab + (size_t)mi * 16 * HIDDEN + k0);
        #pragma unroll
        for (int ni = 0; ni < 4; ++ni) bf[ni] = *(const bf16x8*)(Bb + (size_t)ni * 16 * HIDDEN + k0);
        #pragma unroll
        for (int mi = 0; mi < 4; ++mi)
            #pragma unroll
            for (int ni = 0; ni < 4; ++ni)
                acc[mi][ni] = __builtin_amdgcn_mfma_f32_16x16x32_bf16(a[mi], bf[ni], acc[mi][ni], 0, 0, 0);
    }

    __shared__ float OL[2][32][69];
    #pragma unroll
    for (int half = 0; half < 2; ++half) {
        #pragma unroll
        for (int mm = 0; mm < 2; ++mm) {
            const int mi = half * 2 + mm;
            #pragma unroll
            for (int ni = 0; ni < 4; ++ni)
                #pragma unroll
                for (int r = 0; r < 4; ++r)
                    OL[wave][mm * 16 + hi * 4 + r][ni * 16 + lo] = acc[mi][ni][r];
        }
        #pragma unroll
        for (int i = 0; i < 8; ++i) {
            const int flat = i * 64 + lane;
            const int row = flat >> 4, c = flat & 15;
            float4 v = *(float4*)&OL[wave][row][c * 4];
            const int m = bm + half * 32 + row;
            const float bb = b_out[m];
            v.x += bb; v.y += bb; v.z += bb; v.w += bb;
            *(float4*)(out + ((size_t)b * CIN + m) * NTOK + wn + c * 4) = v;
        }
    }
}

// ---------------------------------------------------------------------------
// Launcher. WS layout (38.8 MB):
//  xt @0 (4.19M) | wqb @4194304 (0.79M) | wob @4980736 (0.26M) |
//  ss @5242880 (32K) | wsc @5275648 (16K) | qk bf16 @5292032 (16.78M) |
//  vb @22069248 (8.39M) | attn_t @30457856 (8.39M)
// ---------------------------------------------------------------------------
extern "C" void kernel_launch(void* const* d_in, const int* in_sizes, int n_in,
                              void* d_out, int out_size, void* d_ws, size_t ws_size,
                              hipStream_t stream) {
    const float* x     = (const float*)d_in[0];
    const float* w_qkv = (const float*)d_in[1];
    const float* w_out = (const float*)d_in[2];
    const float* b_out = (const float*)d_in[3];
    float* out = (float*)d_out;

    char* ws = (char*)d_ws;
    unsigned short* xt  = (unsigned short*)(ws);
    unsigned short* wqb = (unsigned short*)(ws + 4194304);
    unsigned short* wob = (unsigned short*)(ws + 4980736);
    float*          ss  = (float*)(ws + 5242880);
    float*          wsc = (float*)(ws + 5275648);
    unsigned short* qk  = (unsigned short*)(ws + 5292032);
    unsigned short* vb  = (unsigned short*)(ws + 22069248);
    unsigned short* attn_t = (unsigned short*)(ws + 30457856);

    hipMemsetAsync(ss, 0, 8 * 1024 * sizeof(float), stream);

    prep_kernel<<<768, 256, 0, stream>>>(x, w_qkv, w_out, xt, wqb, wob);

    gemm1_kernel<<<dim3(8, 12, 8), 256, 0, stream>>>(wqb, xt, qk, vb, ss);

    wnorm_kernel<<<16, 256, 0, stream>>>(ss, wsc);

    attn_mfma_kernel<<<1024, 128, 0, stream>>>(qk, vb, wsc, attn_t);

    gemm2_kernel<<<dim3(8, 4, 8), 128, 0, stream>>>(wob, attn_t, b_out, out);
}